// Round 10
// baseline (236.986 us; speedup 1.0000x reference)
//
#include <hip/hip_runtime.h>
#include <hip/hip_bf16.h>

// LSTMAggregator — ROUND 15: half-tile tail + Wih-ahead MFMA/VALU overlap.
// R14 (101 us) confirmed: counted-wait barriers + 2-deep pipeline, no spill.
// Remaining losses: (1) ceil(1563/512)=4 straggler — 27 blocks run a 4th
// tile (~25 us phase; R13 proved 3 blocks/CU serializes, so fix the TILES):
// bulk = 1536 = 3*512 exactly, tail = 848 nodes as 53 NPB=16 half-tiles
// (template<R>) -> tail phase ~0.6T. (2) step-serial Wih: 32 Wih MFMAs
// depend only on x (in LDS since prev barrier), not h. Wih-ahead: during
// step k issue accB = bias + Wih*x_{k+1} after the Whh cluster, then run
// activations(accA) — accB retires in the MFMA pipe under the ~700cyc
// VALU/trans block. Staging shifts one step earlier (x0+x1 in prologue,
// write x_{k+2} at end of k); x_j lives in buf[j&1]; single gather set
// (load top-of-k, write end-of-k = full-step vmcnt cover).
//   A-frag: A[m=lane&15][k=(lane>>4)*8+j]   B-frag: B[k][n=lane&15]=W[row][k]
//   C/D: row(node-in-group)=(lane>>4)*4+reg, col=lane&15

#define NN 50000
#define KK 10
#define FF 128
#define HH 64

// ws layout (bf16 elements)
#define WS_WIH_F 0
#define WS_WHH_F 32768
#define WS_WIH_B 49152

#define NPB 32          // bulk nodes per tile
#define NTB 1536        // bulk tiles = 3 * 512 exactly
#define GRID 512        // persistent blocks: 2 per CU
#define TAIL_NODE0 49152
#define TAIL_BLOCKS 53  // 848 remaining nodes = 53 * 16
#define HS 72           // h_lds row stride (shorts)

typedef __bf16 bf16x8 __attribute__((ext_vector_type(8)));
typedef float f32x4 __attribute__((ext_vector_type(4)));
typedef float f32x2 __attribute__((ext_vector_type(2)));

#if __has_builtin(__builtin_amdgcn_exp2f)
#define EXP2(x) __builtin_amdgcn_exp2f(x)
#else
#define EXP2(x) exp2f(x)
#endif

__device__ __forceinline__ float fast_sig(float x) {
    float e = EXP2(x * -1.44269504f);
    return __builtin_amdgcn_rcpf(1.0f + e);
}
__device__ __forceinline__ float fast_tanh(float x) {
    float e = EXP2(x * 2.88539008f);
    return 1.0f - 2.0f * __builtin_amdgcn_rcpf(e + 1.0f);
}
__device__ __forceinline__ f32x2 sig2(f32x2 x) {
    f32x2 t = x * -1.44269504f;                       // v_pk_mul
    f32x2 e = {EXP2(t.x), EXP2(t.y)};
    f32x2 d = e + 1.0f;                               // v_pk_add
    return (f32x2){__builtin_amdgcn_rcpf(d.x), __builtin_amdgcn_rcpf(d.y)};
}
__device__ __forceinline__ f32x2 tanh2(f32x2 x) {
    f32x2 t = x * 2.88539008f;
    f32x2 e = {EXP2(t.x), EXP2(t.y)};
    f32x2 d = e + 1.0f;
    f32x2 r = {__builtin_amdgcn_rcpf(d.x), __builtin_amdgcn_rcpf(d.y)};
    return 1.0f - 2.0f * r;                           // v_pk_fma
}

__global__ void cvt_weights_kernel(const float* __restrict__ Wih_f,
                                   const float* __restrict__ Whh_f,
                                   const float* __restrict__ Wih_b,
                                   __bf16* __restrict__ ws) {
    int i = blockIdx.x * 256 + threadIdx.x;          // 32768 threads
    ws[WS_WIH_F + i] = (__bf16)Wih_f[i];
    if (i < 16384) ws[WS_WHH_F + i] = (__bf16)Whh_f[i];
    ws[WS_WIH_B + i] = (__bf16)Wih_b[i];
}

#define STAGE_LOAD(Gs, kidx)                                                  \
    do {                                                                      \
        const float* _src = tab + (size_t)gq[srow][(kidx)] * FF + spart * 16; \
        _Pragma("unroll")                                                     \
        for (int _j = 0; _j < 4; ++_j) Gs[_j] = *(const f32x4*)(_src + _j * 4);\
    } while (0)

#define STAGE_WRITE(Gs, b)                                                    \
    do {                                                                      \
        bf16x8 _v0, _v1;                                                      \
        _Pragma("unroll")                                                     \
        for (int _e = 0; _e < 4; ++_e) {                                      \
            _v0[_e]     = (__bf16)Gs[0][_e];                                  \
            _v0[4 + _e] = (__bf16)Gs[1][_e];                                  \
            _v1[_e]     = (__bf16)Gs[2][_e];                                  \
            _v1[4 + _e] = (__bf16)Gs[3][_e];                                  \
        }                                                                     \
        char* _row = (char*)(x_lds[(b)] + srow * FF);                         \
        *(bf16x8*)(_row + ((spart * 32)      ^ swW)) = _v0;                   \
        *(bf16x8*)(_row + ((spart * 32 + 16) ^ swW)) = _v1;                   \
    } while (0)

// in-loop barrier: LDS writes visible, global loads stay in flight
#define STEP_BARRIER()                                                        \
    do {                                                                      \
        asm volatile("s_waitcnt lgkmcnt(0)" ::: "memory");                    \
        __builtin_amdgcn_s_barrier();                                         \
        __builtin_amdgcn_sched_barrier(0);                                    \
    } while (0)

template<int R>
__device__ __forceinline__ void lstm_tile(
    int node_base, int tid, int w, int q, int c, int koff, int sw,
    int srow, int spart, int swW,
    const int* __restrict__ nidx, const float* __restrict__ tab,
    const __bf16* __restrict__ ws,
    const float* __restrict__ bih_b, const float* __restrict__ bhh_b,
    const bf16x8 (&bWih)[4][4], const bf16x8 (&bWhh)[4][2],
    const float (&bias)[4],
    __bf16 (*x_lds)[NPB * FF], __bf16 (*h_lds)[NPB * HS], int (*gq)[KK],
    float* __restrict__ out)
{
    __syncthreads();   // previous tile fully retired before gq overwrite
    for (int i = tid; i < R * 16 * KK; i += 256) {
        int r = i / KK, k = i - r * KK;
        int node = min(node_base + r, NN - 1);
        gq[r][k] = nidx[node * KK + k];
    }
    __syncthreads();   // gq visible

    const bool sact = (srow < R * 16);   // staging rows active for this R
    f32x4 GA[4];
    {
        f32x4 GB[4];   // prologue-scoped second set (x1)
        if (sact) { STAGE_LOAD(GA, 0); STAGE_LOAD(GB, 1); }
        __builtin_amdgcn_sched_barrier(0);
        if (sact) { STAGE_WRITE(GA, 0); STAGE_WRITE(GB, 1); }
    }
    STEP_BARRIER();    // x0, x1 visible

    f32x4 acc[2][4][2];   // [phase][gate][node-group]; phase = k&1
    float cst[2][4];
#pragma unroll
    for (int r = 0; r < R; ++r)
#pragma unroll
        for (int e = 0; e < 4; ++e) cst[r][e] = 0.0f;

    // acc[0] = bias + Wih * x0
#pragma unroll
    for (int g = 0; g < 4; ++g)
#pragma unroll
        for (int r = 0; r < R; ++r)
            acc[0][g][r] = (f32x4){bias[g], bias[g], bias[g], bias[g]};
    {
        const char* xb = (const char*)x_lds[0];
#pragma unroll
        for (int r = 0; r < R; ++r) {
            const char* rp = xb + (r * 16 + c) * 256;
            bf16x8 xa[4];
#pragma unroll
            for (int kk = 0; kk < 4; ++kk)
                xa[kk] = *(const bf16x8*)(rp + ((kk * 64 + q * 16) ^ sw));
#pragma unroll
            for (int g = 0; g < 4; ++g)
#pragma unroll
                for (int kk = 0; kk < 4; ++kk)
                    acc[0][g][r] = __builtin_amdgcn_mfma_f32_16x16x32_bf16(
                        xa[kk], bWih[g][kk], acc[0][g][r], 0, 0, 0);
        }
    }

#pragma unroll 2
    for (int k = 0; k < KK; ++k) {
        const int pa = k & 1, pb = (k + 1) & 1;   // static under unroll 2
        if (k + 2 < KK && sact) STAGE_LOAD(GA, k + 2);
        __builtin_amdgcn_sched_barrier(0);

        __builtin_amdgcn_s_setprio(1);
        if (k > 0) {   // Whh * h_{k-1} into acc[pa]; h_{k-1} is in h_lds[pb]
            const __bf16* hb = h_lds[pb];
#pragma unroll
            for (int r = 0; r < R; ++r) {
                bf16x8 ha[2];
#pragma unroll
                for (int kk = 0; kk < 2; ++kk)
                    ha[kk] = *(const bf16x8*)(hb + (r * 16 + c) * HS + kk * 32 + koff);
#pragma unroll
                for (int g = 0; g < 4; ++g)
#pragma unroll
                    for (int kk = 0; kk < 2; ++kk)
                        acc[pa][g][r] = __builtin_amdgcn_mfma_f32_16x16x32_bf16(
                            ha[kk], bWhh[g][kk], acc[pa][g][r], 0, 0, 0);
            }
        }
        if (k + 1 < KK) {   // Wih-ahead: acc[pb] = bias + Wih * x_{k+1}
#pragma unroll
            for (int g = 0; g < 4; ++g)
#pragma unroll
                for (int r = 0; r < R; ++r)
                    acc[pb][g][r] = (f32x4){bias[g], bias[g], bias[g], bias[g]};
            const char* xb = (const char*)x_lds[pb];
#pragma unroll
            for (int r = 0; r < R; ++r) {
                const char* rp = xb + (r * 16 + c) * 256;
                bf16x8 xa[4];
#pragma unroll
                for (int kk = 0; kk < 4; ++kk)
                    xa[kk] = *(const bf16x8*)(rp + ((kk * 64 + q * 16) ^ sw));
#pragma unroll
                for (int g = 0; g < 4; ++g)
#pragma unroll
                    for (int kk = 0; kk < 4; ++kk)
                        acc[pb][g][r] = __builtin_amdgcn_mfma_f32_16x16x32_bf16(
                            xa[kk], bWih[g][kk], acc[pb][g][r], 0, 0, 0);
            }
        }
        __builtin_amdgcn_s_setprio(0);

        // activations(acc[pa]) — VALU/trans pipe, overlaps acc[pb] MFMAs
        const bool last = (k == KK - 1);
        __bf16* hw = h_lds[pa];
#pragma unroll
        for (int r = 0; r < R; ++r)
#pragma unroll
            for (int p = 0; p < 2; ++p) {
                f32x2 ai = {acc[pa][0][r][2 * p], acc[pa][0][r][2 * p + 1]};
                f32x2 af = {acc[pa][1][r][2 * p], acc[pa][1][r][2 * p + 1]};
                f32x2 ag = {acc[pa][2][r][2 * p], acc[pa][2][r][2 * p + 1]};
                f32x2 ao = {acc[pa][3][r][2 * p], acc[pa][3][r][2 * p + 1]};
                f32x2 gi = sig2(ai);
                f32x2 gf = sig2(af);
                f32x2 gg = tanh2(ag);
                f32x2 go = sig2(ao);
                f32x2 cc = {cst[r][2 * p], cst[r][2 * p + 1]};
                f32x2 cn = gf * cc + gi * gg;        // v_pk_mul + v_pk_fma
                cst[r][2 * p]     = cn.x;
                cst[r][2 * p + 1] = cn.y;
                f32x2 h = go * tanh2(cn);
                hw[(r * 16 + q * 4 + 2 * p)     * HS + w * 16 + c] = (__bf16)h.x;
                hw[(r * 16 + q * 4 + 2 * p + 1) * HS + w * 16 + c] = (__bf16)h.y;
                if (last) {
                    int node = node_base + r * 16 + q * 4 + 2 * p;
                    if (node < NN)     out[(size_t)node * 128 + w * 16 + c] = h.x;
                    if (node + 1 < NN) out[(size_t)(node + 1) * 128 + w * 16 + c] = h.y;
                }
            }

        // write-late: x_{k+2} -> buf[pa] (x_k's buffer; nobody reads it now)
        if (k + 2 < KK && sact) STAGE_WRITE(GA, pa);
        STEP_BARRIER();
    }

    // ---- backward direction: one step on x9 (in x_lds[1]), zero state.
    // Per-gate sequential weight loads (16-reg spike).
    {
        const int gb[3] = {0, 2, 3};    // gates i, g, o (f irrelevant: c0=0)
        const char* xb = (const char*)x_lds[1];
        f32x4 ab[3][2];
#pragma unroll
        for (int j = 0; j < 3; ++j) {
            int row = (gb[j] * 4 + w) * 16 + c;
            bf16x8 bW[4];
#pragma unroll
            for (int kk = 0; kk < 4; ++kk)
                bW[kk] = *(const bf16x8*)(ws + WS_WIH_B + row * FF + kk * 32 + koff);
            int u = gb[j] * 64 + w * 16 + c;
            float bb = bih_b[u] + bhh_b[u];
#pragma unroll
            for (int r = 0; r < R; ++r) {
                f32x4 a = (f32x4){bb, bb, bb, bb};
                const char* rp = xb + (r * 16 + c) * 256;
#pragma unroll
                for (int kk = 0; kk < 4; ++kk) {
                    bf16x8 xa = *(const bf16x8*)(rp + ((kk * 64 + q * 16) ^ sw));
                    a = __builtin_amdgcn_mfma_f32_16x16x32_bf16(xa, bW[kk], a, 0, 0, 0);
                }
                ab[j][r] = a;
            }
        }
#pragma unroll
        for (int r = 0; r < R; ++r)
#pragma unroll
            for (int reg = 0; reg < 4; ++reg) {
                float gi = fast_sig(ab[0][r][reg]);
                float gg = fast_tanh(ab[1][r][reg]);
                float go = fast_sig(ab[2][r][reg]);
                float hb2 = go * fast_tanh(gi * gg);
                int node = node_base + r * 16 + q * 4 + reg;
                if (node < NN) out[(size_t)node * 128 + 64 + w * 16 + c] = hb2;
            }
    }
}

__global__ __launch_bounds__(256, 2) void lstm_agg_kernel(
    const int* __restrict__ nidx,
    const float* __restrict__ tab,
    const float* __restrict__ bih_f,
    const float* __restrict__ bhh_f,
    const float* __restrict__ bih_b,
    const float* __restrict__ bhh_b,
    const __bf16* __restrict__ ws,
    float* __restrict__ out)
{
    __shared__ __bf16 x_lds[2][NPB * FF];   // 2 x 8 KB bf16, 16B-slot swizzled
    __shared__ __bf16 h_lds[2][NPB * HS];   // 2 x 4.5 KB, double-buffered
    __shared__ int    gq[NPB][KK];          // 1.25 KB        (total 26.9 KB)

    const int tid  = threadIdx.x;
    const int w    = tid >> 6;        // wave id: owns units w*16..w*16+15
    const int lane = tid & 63;
    const int q    = lane >> 4;
    const int c    = lane & 15;
    const int koff = q * 8;
    const int sw   = (c & 7) << 4;    // frag-read de-swizzle

    const int srow  = tid >> 3;       // staging row
    const int spart = tid & 7;
    const int swW   = (srow & 7) << 4;

    // weight B-fragments + biases: register-resident across ALL tiles
    bf16x8 bWih[4][4], bWhh[4][2];
#pragma unroll
    for (int g = 0; g < 4; ++g) {
        int row = (g * 4 + w) * 16 + c;        // gate row g*64 + w*16 + c
#pragma unroll
        for (int kk = 0; kk < 4; ++kk)
            bWih[g][kk] = *(const bf16x8*)(ws + WS_WIH_F + row * FF + kk * 32 + koff);
#pragma unroll
        for (int kk = 0; kk < 2; ++kk)
            bWhh[g][kk] = *(const bf16x8*)(ws + WS_WHH_F + row * HH + kk * 32 + koff);
    }
    float bias[4];
#pragma unroll
    for (int g = 0; g < 4; ++g) {
        int u = g * 64 + w * 16 + c;
        bias[g] = bih_f[u] + bhh_f[u];
    }

    for (int t = blockIdx.x; t < NTB; t += GRID)
        lstm_tile<2>(t * NPB, tid, w, q, c, koff, sw, srow, spart, swW,
                     nidx, tab, ws, bih_b, bhh_b, bWih, bWhh, bias,
                     x_lds, h_lds, gq, out);

    if (blockIdx.x < TAIL_BLOCKS)   // 848 tail nodes as 53 half-tiles
        lstm_tile<1>(TAIL_NODE0 + (int)blockIdx.x * 16, tid, w, q, c, koff, sw,
                     srow, spart, swW,
                     nidx, tab, ws, bih_b, bhh_b, bWih, bWhh, bias,
                     x_lds, h_lds, gq, out);
}

extern "C" void kernel_launch(void* const* d_in, const int* in_sizes, int n_in,
                              void* d_out, int out_size, void* d_ws, size_t ws_size,
                              hipStream_t stream) {
    const int*   nidx  = (const int*)d_in[0];
    const float* tab   = (const float*)d_in[1];
    const float* Wih_f = (const float*)d_in[2];
    const float* Whh_f = (const float*)d_in[3];
    const float* bih_f = (const float*)d_in[4];
    const float* bhh_f = (const float*)d_in[5];
    const float* Wih_b = (const float*)d_in[6];
    // d_in[7] = Whh_b: mathematically unused (h0 = 0 for the backward stream)
    const float* bih_b = (const float*)d_in[8];
    const float* bhh_b = (const float*)d_in[9];
    __bf16* ws  = (__bf16*)d_ws;      // 160 KB scratch
    float*  out = (float*)d_out;      // output is f32

    hipLaunchKernelGGL(cvt_weights_kernel, dim3(32768 / 256), dim3(256), 0, stream,
                       Wih_f, Whh_f, Wih_b, ws);

    hipLaunchKernelGGL(lstm_agg_kernel, dim3(GRID), dim3(256), 0, stream,
                       nidx, tab, bih_f, bhh_f, bih_b, bhh_b, ws, out);
}